// Round 14
// baseline (124.247 us; speedup 1.0000x reference)
//
#include <hip/hip_runtime.h>
#include <hip/hip_bf16.h>
#include <math.h>

// Problem constants (fixed shape)
#define T_ 1024
#define H_ 1024
#define I_ 2048
#define E_ 8
#define NSLOT 2048

// GEMM tiling
#define BM 128
#define BK 32
#define BN1 64                      // gemm1 n-tile
#define BN2 64                      // gemm2 n-tile
#define NCHUNK_CAP 24               // sum ceil(cnt_e/128) <= 23
#define SPLITK2 2                   // gemm2 split-K (I=2048 -> 2x1024)

typedef __attribute__((ext_vector_type(8))) short bf16x8;
typedef __attribute__((ext_vector_type(4))) float f32x4;
typedef __attribute__((ext_vector_type(4))) unsigned uint4v;
typedef __attribute__((ext_vector_type(2))) unsigned uint2v;

#define MFMA_BF16 __builtin_amdgcn_mfma_f32_16x16x32_bf16

__device__ __forceinline__ short f2bf(float f) {
  union { float f; unsigned u; } v; v.f = f;
  unsigned r = v.u + 0x7FFFu + ((v.u >> 16) & 1u);
  return (short)(r >> 16);
}
__device__ __forceinline__ unsigned cvtpk(float lo, float hi) {
  unsigned r;
  asm("v_cvt_pk_bf16_f32 %0, %1, %2" : "=v"(r) : "v"(lo), "v"(hi));
  return r;
}
// async 16B global->LDS (lane i writes lds_base + i*16) — gemm2 only now
__device__ __forceinline__ void gll16(const void* g, void* l) {
  __builtin_amdgcn_global_load_lds(
      (const __attribute__((address_space(1))) void*)g,
      (__attribute__((address_space(3))) void*)l, 16, 0, 0);
}

// gemm1 barrier: only LDS ordering is manual (sB dbuf). All VMEM->VGPR deps
// (A-fragment gathers, B reg loads) are compiler-tracked; loads stay in
// flight across the barrier and the compiler inserts vmcnt waits at use.
__device__ __forceinline__ void lds_barrier() {
  __builtin_amdgcn_sched_barrier(0);
  asm volatile("s_waitcnt lgkmcnt(0)" ::: "memory");
  __builtin_amdgcn_s_barrier();
  __builtin_amdgcn_sched_barrier(0);
}
// gemm2 pipelined barrier (round-6 proven): allow 6 vmem in flight.
__device__ __forceinline__ void pipe_barrier6() {
  __builtin_amdgcn_sched_barrier(0);
  asm volatile("s_waitcnt vmcnt(6) lgkmcnt(0)" ::: "memory");
  __builtin_amdgcn_s_barrier();
  __builtin_amdgcn_sched_barrier(0);
}
__device__ __forceinline__ void drain_barrier() {
  __builtin_amdgcn_sched_barrier(0);
  asm volatile("s_waitcnt vmcnt(0) lgkmcnt(0)" ::: "memory");
  __builtin_amdgcn_s_barrier();
  __builtin_amdgcn_sched_barrier(0);
}

// B-tile swizzle ([n][k] bf16, rows of 64B) — gemm2 layout.
__device__ __forceinline__ unsigned bswz(int n, int kbyte) {
  return (unsigned)(n * 64 + (kbyte ^ (((n >> 2) & 3) << 4)));
}
// Unified tile swizzle ([rows][32] bf16, four 16B granules) — gemm1 sB.
__device__ __forceinline__ int rswz(int row) { return (row >> 1) & 3; }
__device__ __forceinline__ unsigned tile_addr(int row, int g) {
  return (unsigned)(row * 64 + (((g ^ rswz(row)) & 3) << 4));
}

// ---------------------------------------------------------------------------
// Kernel 0: fused hs f32->bf16 convert (all blocks) + routing build (block 0)
// meta[0..8]=offs, meta[9]=nchunks, meta[16+c] = e | (row0<<8)
// ---------------------------------------------------------------------------
__global__ __launch_bounds__(256) void k_prep_build(
    const float* __restrict__ hs, short* __restrict__ hs_bf,
    const float* __restrict__ aff, const int* __restrict__ eidx,
    int* __restrict__ meta, int* __restrict__ slot_tok, float* __restrict__ slot_w) {
  int i = (blockIdx.x * 256 + threadIdx.x) * 8;
  float4 v0 = *(const float4*)&hs[i];
  float4 v1 = *(const float4*)&hs[i + 4];
  uint4v p;
  p.x = cvtpk(v0.x, v0.y); p.y = cvtpk(v0.z, v0.w);
  p.z = cvtpk(v1.x, v1.y); p.w = cvtpk(v1.z, v1.w);
  *(uint4v*)&hs_bf[i] = p;

  if (blockIdx.x != 0) return;
  __shared__ int cnt[E_];
  __shared__ int soff[E_ + 1];
  int t = threadIdx.x;
  if (t < E_) cnt[t] = 0;
  __syncthreads();
  int e0a[4], e1a[4], r0a[4], r1a[4];
  float w0a[4], w1a[4];
#pragma unroll
  for (int j = 0; j < 4; ++j) {
    int tok = t + 256 * j;
    int e0 = eidx[tok * 2 + 0];
    int e1 = eidx[tok * 2 + 1];
    float a0 = aff[tok * E_ + e0];
    float a1 = aff[tok * E_ + e1];
    float inv = 1.0f / (a0 + a1);
    r0a[j] = atomicAdd(&cnt[e0], 1);
    r1a[j] = atomicAdd(&cnt[e1], 1);
    e0a[j] = e0; e1a[j] = e1;
    w0a[j] = a0 * inv; w1a[j] = a1 * inv;
  }
  __syncthreads();
  if (t == 0) {
    int s = 0;
    for (int e = 0; e < E_; ++e) { soff[e] = s; s += cnt[e]; }
    soff[E_] = s;
    int nc = 0;
    for (int e = 0; e < E_; ++e)
      for (int c = soff[e]; c < soff[e] + cnt[e]; c += BM)
        meta[16 + nc++] = e | (c << 8);
    meta[9] = nc;
  }
  __syncthreads();
  if (t <= E_) meta[t] = soff[t];
#pragma unroll
  for (int j = 0; j < 4; ++j) {
    int tok = t + 256 * j;
    int s0 = soff[e0a[j]] + r0a[j];
    int s1 = soff[e1a[j]] + r1a[j];
    slot_tok[s0] = tok; slot_w[s0] = w0a[j];
    slot_tok[s1] = tok; slot_w[s1] = w1a[j];
  }
}

// ---------------------------------------------------------------------------
// Kernel 1: grouped GEMM  act[slot,i] = silu(X@Wg) * (X@Wu)
// A fragments read DIRECTLY from L2 (per-lane contiguous 16B of hs_bf),
// prefetched 1 iter ahead into registers — no sA, no glls, no A conflicts.
// B: round-9 proven path (f32 reg-stage -> cvtpk -> swizzled LDS dbuf).
// LDS work/iter drops ~950 -> ~250 cy (the binding pipe).
// ---------------------------------------------------------------------------
__global__ __launch_bounds__(256, 2) void k_gemm1(
    const short* __restrict__ hs_bf, const float* __restrict__ wg,
    const float* __restrict__ wu, const int* __restrict__ meta,
    const int* __restrict__ slot_tok, short* __restrict__ act) {
  int nch = meta[9];
  if (blockIdx.y >= nch) return;
  int ck = meta[16 + blockIdx.y];
  int e = ck & 255;
  int row0 = ck >> 8;
  int rows = min(BM, meta[1 + e] - row0);
  int i0 = blockIdx.x * BN1;

  __shared__ short sB[2][2][BN1 * BK];   // 16KB dbuf x {gate,up}, swizzled

  int tid = threadIdx.x;
  int lane = tid & 63;
  int w = tid >> 6;                 // 0..3
  int wm = w >> 1, wn = w & 1;      // 2m x 2n
  int lr = lane & 15;
  int g = lane >> 4;                // fragment k-slot (16B granule)
  int lk = g * 8;                   // fragment k element offset

  const float* wgE = wg + (size_t)e * H_ * I_;
  const float* wuE = wu + (size_t)e * H_ * I_;

  // A fragment base pointers (per-lane, k-invariant): lane reads 16B of
  // token row for m = wm*64 + mf*16 + lr at k = t*BK + lk.
  const short* aP[4];
#pragma unroll
  for (int mf = 0; mf < 4; ++mf) {
    int m = wm * 64 + mf * 16 + lr;
    int tok = slot_tok[row0 + min(m, rows - 1)];
    aP[mf] = hs_bf + (size_t)tok * H_ + lk;
  }

  // B staging: thread owns one mat, 4 k-rows x 4 n-cols.
  int mat = tid >> 7;               // 0 gate, 1 up
  int kq = (tid >> 4) & 7;          // k-quad: rows 4kq..4kq+3
  int nq = tid & 15;                // n-quad: cols 4nq..4nq+3
  const float* srcB = (mat ? wuE : wgE) + (size_t)(4 * kq) * I_ + i0 + 4 * nq;

  f32x4 accg[4][2], accu[4][2];
#pragma unroll
  for (int mf = 0; mf < 4; ++mf)
#pragma unroll
    for (int nf = 0; nf < 2; ++nf) {
      accg[mf][nf] = (f32x4){0.f, 0.f, 0.f, 0.f};
      accu[mf][nf] = (f32x4){0.f, 0.f, 0.f, 0.f};
    }

  f32x4 bs0[4], bs1[4];        // two B-staging reg sets
  bf16x8 aS0[4], aS1[4];       // two A-fragment reg sets (static-indexed)

  const int NT = H_ / BK;   // 32

#define G1_LOADB(C, T) do {                                                    \
    const float* sb_ = srcB + (size_t)(T) * BK * I_;                           \
    C[0] = *(const f32x4*)(sb_);                                               \
    C[1] = *(const f32x4*)(sb_ + I_);                                          \
    C[2] = *(const f32x4*)(sb_ + 2 * I_);                                      \
    C[3] = *(const f32x4*)(sb_ + 3 * I_);                                      \
  } while (0)
#define G1_CONV(BUF, C) do {                                                   \
    char* dst_ = (char*)&sB[(BUF)][mat][0];                                    \
    _Pragma("unroll")                                                          \
    for (int c_ = 0; c_ < 4; ++c_) {                                           \
      int n_ = 4 * nq + c_;                                                    \
      uint2v wv_;                                                              \
      wv_.x = cvtpk(C[0][c_], C[1][c_]);                                       \
      wv_.y = cvtpk(C[2][c_], C[3][c_]);                                       \
      *(uint2v*)(dst_ + tile_addr(n_, kq >> 1) + ((kq & 1) << 3)) = wv_;       \
    }                                                                          \
  } while (0)
#define G1_LOADA(A, T) do {                                                    \
    A[0] = *(const bf16x8*)(aP[0] + (size_t)(T) * BK);                         \
    A[1] = *(const bf16x8*)(aP[1] + (size_t)(T) * BK);                         \
    A[2] = *(const bf16x8*)(aP[2] + (size_t)(T) * BK);                         \
    A[3] = *(const bf16x8*)(aP[3] + (size_t)(T) * BK);                         \
  } while (0)
// Iter t (buf U=t&1): prefetch A(t+1), load B regs (t+2), MFMA from
// registers+sB[U], conv bsC -> sB[U^1], LDS-only barrier.
#define G1_ITER(U, AC, AN, bsL, bsC) do {                                      \
    int t_ = base + (U);                                                       \
    if (t_ + 1 < NT) G1_LOADA(AN, t_ + 1);                                     \
    if (t_ + 2 < NT) G1_LOADB(bsL, t_ + 2);                                    \
    const char* pg = (const char*)&sB[(U)][0][0];                              \
    const char* pu = (const char*)&sB[(U)][1][0];                              \
    unsigned ob0 = tile_addr(wn * 32 + lr, g);                                 \
    unsigned ob1 = tile_addr(wn * 32 + 16 + lr, g);                            \
    bf16x8 g0 = *(const bf16x8*)(pg + ob0);                                    \
    bf16x8 g1 = *(const bf16x8*)(pg + ob1);                                    \
    bf16x8 u0 = *(const bf16x8*)(pu + ob0);                                    \
    bf16x8 u1 = *(const bf16x8*)(pu + ob1);                                    \
    accg[0][0] = MFMA_BF16(AC[0], g0, accg[0][0], 0, 0, 0);                    \
    accg[0][1] = MFMA_BF16(AC[0], g1, accg[0][1], 0, 0, 0);                    \
    accg[1][0] = MFMA_BF16(AC[1], g0, accg[1][0], 0, 0, 0);                    \
    accg[1][1] = MFMA_BF16(AC[1], g1, accg[1][1], 0, 0, 0);                    \
    accg[2][0] = MFMA_BF16(AC[2], g0, accg[2][0], 0, 0, 0);                    \
    accg[2][1] = MFMA_BF16(AC[2], g1, accg[2][1], 0, 0, 0);                    \
    accg[3][0] = MFMA_BF16(AC[3], g0, accg[3][0], 0, 0, 0);                    \
    accg[3][1] = MFMA_BF16(AC[3], g1, accg[3][1], 0, 0, 0);                    \
    accu[0][0] = MFMA_BF16(AC[0], u0, accu[0][0], 0, 0, 0);                    \
    accu[0][1] = MFMA_BF16(AC[0], u1, accu[0][1], 0, 0, 0);                    \
    accu[1][0] = MFMA_BF16(AC[1], u0, accu[1][0], 0, 0, 0);                    \
    accu[1][1] = MFMA_BF16(AC[1], u1, accu[1][1], 0, 0, 0);                    \
    accu[2][0] = MFMA_BF16(AC[2], u0, accu[2][0], 0, 0, 0);                    \
    accu[2][1] = MFMA_BF16(AC[2], u1, accu[2][1], 0, 0, 0);                    \
    accu[3][0] = MFMA_BF16(AC[3], u0, accu[3][0], 0, 0, 0);                    \
    accu[3][1] = MFMA_BF16(AC[3], u1, accu[3][1], 0, 0, 0);                    \
    if (t_ + 1 < NT) G1_CONV((U) ^ 1, bsC);                                    \
    lds_barrier();                                                             \
  } while (0)

  // prologue: A regs tile 0; B regs tiles 0,1; conv tile 0 -> sB[0]
  G1_LOADA(aS0, 0);
  G1_LOADB(bs0, 0);
  G1_LOADB(bs1, 1);
  G1_CONV(0, bs0);
  lds_barrier();

  for (int base = 0; base < NT; base += 2) {
    G1_ITER(0, aS0, aS1, bs0, bs1);
    G1_ITER(1, aS1, aS0, bs1, bs0);
  }
#undef G1_ITER
#undef G1_LOADA
#undef G1_CONV
#undef G1_LOADB

  // epilogue: silu(g)*u -> bf16 act
#pragma unroll
  for (int mf = 0; mf < 4; ++mf) {
#pragma unroll
    for (int r = 0; r < 4; ++r) {
      int m = wm * 64 + mf * 16 + g * 4 + r;
      if (m < rows) {
#pragma unroll
        for (int nf = 0; nf < 2; ++nf) {
          float gv = accg[mf][nf][r];
          float uv = accu[mf][nf][r];
          float sg = 1.0f / (1.0f + __expf(-gv));
          act[(size_t)(row0 + m) * I_ + i0 + wn * 32 + nf * 16 + lr] = f2bf(gv * sg * uv);
        }
      }
    }
  }
}

// ---------------------------------------------------------------------------
// Kernel 2: grouped GEMM  out[tok,h] += w * (act[slot,:] @ Wd[e])  [round-6]
// 512 thr (8 waves, 4m x 2n, wave-tile 32x32), split-K x2, depth-3 pipeline:
// sA ring-4 linear via gll, sB ring-2 bswz, B reg ring-4, vmcnt(6).
// ---------------------------------------------------------------------------
__global__ __launch_bounds__(512, 4) void k_gemm2(
    const short* __restrict__ act, const float* __restrict__ wd,
    const int* __restrict__ meta, const int* __restrict__ slot_tok,
    const float* __restrict__ slot_w, float* __restrict__ out) {
  int nch = meta[9];
  if (blockIdx.y >= nch) return;
  int ck = meta[16 + blockIdx.y];
  int e = ck & 255;
  int row0 = ck >> 8;
  int rows = min(BM, meta[1 + e] - row0);
  int h0 = blockIdx.x * BN2;
  int kbase = blockIdx.z * (I_ / SPLITK2);

  __shared__ short sA[4][BM * BK];   // ring-4, linear [row][k]
  __shared__ short sB[2][BN2 * BK];  // ring-2, swizzled [n][k]

  int tid = threadIdx.x;
  int lane = tid & 63;
  int w = tid >> 6;
  int wm = w >> 1, wn = w & 1;
  int lr = lane & 15;
  int lk = (lane >> 4) * 8;

  const float* wdE = wd + (size_t)e * I_ * H_;

  int ra = min(16 * w + (lane >> 2), rows - 1);
  const short* srcA = act + (size_t)(row0 + ra) * I_ + kbase + (lane & 3) * 8;
  int up = tid >> 5;                   // k-pair 0..15
  int n2 = (tid & 31) * 2;
  const float* srcB = wdE + (size_t)(kbase + 2 * up) * H_ + h0 + n2;

  f32x4 acc[2][2];
#pragma unroll
  for (int mr = 0; mr < 2; ++mr)
#pragma unroll
    for (int nr = 0; nr < 2; ++nr)
      acc[mr][nr] = (f32x4){0.f, 0.f, 0.f, 0.f};

  float2 bs[4][2];   // B reg ring-4

  // prologue: tiles 0,1,2
#pragma unroll
  for (int p = 0; p < 3; ++p) {
    gll16(srcA + p * BK, &sA[p][w * 512]);
    bs[p][0] = *(const float2*)(srcB + (size_t)(p * BK) * H_);
    bs[p][1] = *(const float2*)(srcB + (size_t)(p * BK + 1) * H_);
  }
  *(unsigned*)((char*)&sB[0][0] + bswz(n2, 4 * up))     = cvtpk(bs[0][0].x, bs[0][1].x);
  *(unsigned*)((char*)&sB[0][0] + bswz(n2 + 1, 4 * up)) = cvtpk(bs[0][0].y, bs[0][1].y);
  drain_barrier();

  const int NT = (I_ / SPLITK2) / BK;   // 32

#define G2_ITER(U, base_) do {                                                 \
    int t_ = (base_) + (U);                                                    \
    if (t_ + 3 < NT) {                                                         \
      int k3 = (t_ + 3) * BK;                                                  \
      gll16(srcA + k3, &sA[((U) + 3) & 3][w * 512]);                           \
      bs[((U) + 3) & 3][0] = *(const float2*)(srcB + (size_t)k3 * H_);         \
      bs[((U) + 3) & 3][1] = *(const float2*)(srcB + (size_t)(k3 + 1) * H_);   \
    }                                                                          \
    bf16x8 a0 = *(const bf16x8*)&sA[(U)][(wm * 32 + lr) * BK + lk];            \
    bf16x8 a1 = *(const bf16x8*)&sA[(U)][(wm * 32 + 16 + lr) * BK + lk];       \
    bf16x8 b0 = *(const bf16x8*)((const char*)&sB[(U) & 1][0]                  \
                                 + bswz(wn * 32 + lr, lk * 2));                \
    bf16x8 b1 = *(const bf16x8*)((const char*)&sB[(U) & 1][0]                  \
                                 + bswz(wn * 32 + 16 + lr, lk * 2));           \
    acc[0][0] = MFMA_BF16(a0, b0, acc[0][0], 0, 0, 0);                         \
    acc[0][1] = MFMA_BF16(a0, b1, acc[0][1], 0, 0, 0);                         \
    acc[1][0] = MFMA_BF16(a1, b0, acc[1][0], 0, 0, 0);                         \
    acc[1][1] = MFMA_BF16(a1, b1, acc[1][1], 0, 0, 0);                         \
    if (t_ + 1 < NT) {                                                         \
      int s_ = ((U) + 1) & 3;                                                  \
      *(unsigned*)((char*)&sB[((U) + 1) & 1][0] + bswz(n2, 4 * up))            \
          = cvtpk(bs[s_][0].x, bs[s_][1].x);                                   \
      *(unsigned*)((char*)&sB[((U) + 1) & 1][0] + bswz(n2 + 1, 4 * up))        \
          = cvtpk(bs[s_][0].y, bs[s_][1].y);                                   \
    }                                                                          \
    pipe_barrier6();                                                           \
  } while (0)

  for (int base = 0; base < NT; base += 4) {
    G2_ITER(0, base);
    G2_ITER(1, base);
    G2_ITER(2, base);
    G2_ITER(3, base);
  }
#undef G2_ITER

  // epilogue: scale by combine weight, scatter-add
#pragma unroll
  for (int mr = 0; mr < 2; ++mr) {
#pragma unroll
    for (int r = 0; r < 4; ++r) {
      int m = wm * 32 + mr * 16 + (lane >> 4) * 4 + r;
      if (m < rows) {
        int gs = row0 + m;
        float wc = slot_w[gs];
        int tok = slot_tok[gs];
#pragma unroll
        for (int nr = 0; nr < 2; ++nr)
          atomicAdd(&out[(size_t)tok * H_ + h0 + wn * 32 + nr * 16 + lr],
                    acc[mr][nr][r] * wc);
      }
    }
  }
}

// ---------------------------------------------------------------------------
extern "C" void kernel_launch(void* const* d_in, const int* in_sizes, int n_in,
                              void* d_out, int out_size, void* d_ws, size_t ws_size,
                              hipStream_t stream) {
  const float* hs   = (const float*)d_in[0];
  const float* aff  = (const float*)d_in[1];
  const int*   eidx = (const int*)d_in[2];
  const float* wg   = (const float*)d_in[3];
  const float* wu   = (const float*)d_in[4];
  const float* wd   = (const float*)d_in[5];
  float* out = (float*)d_out;

  char* ws = (char*)d_ws;
  int*   meta     = (int*)ws;                            // 256B reserved
  int*   slot_tok = (int*)(ws + 256);                    // 2048 ints
  float* slot_w   = (float*)(ws + 256 + NSLOT * 4);      // 2048 floats
  short* hs_bf    = (short*)(ws + 256 + NSLOT * 8);      // 2MB bf16 hs
  short* act      = (short*)(ws + 256 + NSLOT * 8 + (size_t)T_ * H_ * 2);  // 8MB

  hipMemsetAsync(d_out, 0, (size_t)out_size * sizeof(float), stream);
  k_prep_build<<<(T_ * H_) / (256 * 8), 256, 0, stream>>>(
      hs, hs_bf, aff, eidx, meta, slot_tok, slot_w);
  k_gemm1<<<dim3(I_ / BN1, NCHUNK_CAP), 256, 0, stream>>>(
      hs_bf, wg, wu, meta, slot_tok, act);
  k_gemm2<<<dim3(H_ / BN2, NCHUNK_CAP, SPLITK2), 512, 0, stream>>>(
      act, wd, meta, slot_tok, slot_w, out);
}

// Round 15
// 101.506 us; speedup vs baseline: 1.2240x; 1.2240x over previous
//
#include <hip/hip_runtime.h>
#include <hip/hip_bf16.h>
#include <math.h>

// Problem constants (fixed shape)
#define T_ 1024
#define H_ 1024
#define I_ 2048
#define E_ 8
#define NSLOT 2048

// GEMM tiling
#define BM 128
#define BK 32
#define BN1 64                      // gemm1 n-tile
#define BN2 64                      // gemm2 n-tile
#define NCHUNK_CAP 24               // sum ceil(cnt_e/128) <= 23
#define SPLITK2 2                   // gemm2 split-K (I=2048 -> 2x1024)

typedef __attribute__((ext_vector_type(8))) short bf16x8;
typedef __attribute__((ext_vector_type(4))) float f32x4;
typedef __attribute__((ext_vector_type(4))) unsigned uint4v;
typedef __attribute__((ext_vector_type(2))) unsigned uint2v;

#define MFMA_BF16 __builtin_amdgcn_mfma_f32_16x16x32_bf16

__device__ __forceinline__ short f2bf(float f) {
  union { float f; unsigned u; } v; v.f = f;
  unsigned r = v.u + 0x7FFFu + ((v.u >> 16) & 1u);
  return (short)(r >> 16);
}
__device__ __forceinline__ unsigned cvtpk(float lo, float hi) {
  unsigned r;
  asm("v_cvt_pk_bf16_f32 %0, %1, %2" : "=v"(r) : "v"(lo), "v"(hi));
  return r;
}
// async 16B global->LDS (lane i writes lds_base + i*16)
__device__ __forceinline__ void gll16(const void* g, void* l) {
  __builtin_amdgcn_global_load_lds(
      (const __attribute__((address_space(1))) void*)g,
      (__attribute__((address_space(3))) void*)l, 16, 0, 0);
}

// Counted-vmcnt pipelined barrier: allow 6 vmem (one iteration's issue for
// gemm1 depth-2 / two iterations' for gemm2 depth-3) to stay in flight.
__device__ __forceinline__ void pipe_barrier6() {
  __builtin_amdgcn_sched_barrier(0);
  asm volatile("s_waitcnt vmcnt(6) lgkmcnt(0)" ::: "memory");
  __builtin_amdgcn_s_barrier();
  __builtin_amdgcn_sched_barrier(0);
}
__device__ __forceinline__ void drain_barrier() {
  __builtin_amdgcn_sched_barrier(0);
  asm volatile("s_waitcnt vmcnt(0) lgkmcnt(0)" ::: "memory");
  __builtin_amdgcn_s_barrier();
  __builtin_amdgcn_sched_barrier(0);
}

// B-tile swizzle ([n][k] bf16, rows of 64B) — round-4/6 gemm2 layout.
__device__ __forceinline__ unsigned bswz(int n, int kbyte) {
  return (unsigned)(n * 64 + (kbyte ^ (((n >> 2) & 3) << 4)));
}
// Unified tile swizzle ([rows][32] bf16, four 16B granules) — round-7 gemm1.
__device__ __forceinline__ int rswz(int row) { return (row >> 1) & 3; }
__device__ __forceinline__ unsigned tile_addr(int row, int g) {
  return (unsigned)(row * 64 + (((g ^ rswz(row)) & 3) << 4));
}

// ---------------------------------------------------------------------------
// Kernel 0: fused hs f32->bf16 convert (all blocks) + routing build (block 0)
// meta[0..8]=offs, meta[9]=nchunks, meta[16+c] = e | (row0<<8)
// ---------------------------------------------------------------------------
__global__ __launch_bounds__(256) void k_prep_build(
    const float* __restrict__ hs, short* __restrict__ hs_bf,
    const float* __restrict__ aff, const int* __restrict__ eidx,
    int* __restrict__ meta, int* __restrict__ slot_tok, float* __restrict__ slot_w) {
  // ---- prep slice (all 512 blocks) ----
  int i = (blockIdx.x * 256 + threadIdx.x) * 8;
  float4 v0 = *(const float4*)&hs[i];
  float4 v1 = *(const float4*)&hs[i + 4];
  uint4v p;
  p.x = cvtpk(v0.x, v0.y); p.y = cvtpk(v0.z, v0.w);
  p.z = cvtpk(v1.x, v1.y); p.w = cvtpk(v1.z, v1.w);
  *(uint4v*)&hs_bf[i] = p;

  // ---- build (block 0 only): 256 threads x 4 tokens each ----
  if (blockIdx.x != 0) return;
  __shared__ int cnt[E_];
  __shared__ int soff[E_ + 1];
  int t = threadIdx.x;
  if (t < E_) cnt[t] = 0;
  __syncthreads();
  int e0a[4], e1a[4], r0a[4], r1a[4];
  float w0a[4], w1a[4];
#pragma unroll
  for (int j = 0; j < 4; ++j) {
    int tok = t + 256 * j;
    int e0 = eidx[tok * 2 + 0];
    int e1 = eidx[tok * 2 + 1];
    float a0 = aff[tok * E_ + e0];
    float a1 = aff[tok * E_ + e1];
    float inv = 1.0f / (a0 + a1);
    r0a[j] = atomicAdd(&cnt[e0], 1);
    r1a[j] = atomicAdd(&cnt[e1], 1);
    e0a[j] = e0; e1a[j] = e1;
    w0a[j] = a0 * inv; w1a[j] = a1 * inv;
  }
  __syncthreads();
  if (t == 0) {
    int s = 0;
    for (int e = 0; e < E_; ++e) { soff[e] = s; s += cnt[e]; }
    soff[E_] = s;
    int nc = 0;
    for (int e = 0; e < E_; ++e)
      for (int c = soff[e]; c < soff[e] + cnt[e]; c += BM)
        meta[16 + nc++] = e | (c << 8);
    meta[9] = nc;
  }
  __syncthreads();
  if (t <= E_) meta[t] = soff[t];
#pragma unroll
  for (int j = 0; j < 4; ++j) {
    int tok = t + 256 * j;
    int s0 = soff[e0a[j]] + r0a[j];
    int s1 = soff[e1a[j]] + r1a[j];
    slot_tok[s0] = tok; slot_w[s0] = w0a[j];
    slot_tok[s1] = tok; slot_w[s1] = w1a[j];
  }
}

// ---------------------------------------------------------------------------
// Kernel 1: grouped GEMM  act[slot,i] = silu(X@Wg) * (X@Wu)   [round-7 form]
// 256 thr (4 waves, 2m x 2n), wave-tile 64x32 per mat (Mf=4, Nf=2):
// 8 LDS reads feed 16 MFMA. Depth-2 counted-vmcnt pipeline:
// sA ring-4 (source-swizzled gll), sB dbuf (reg-staged f32 -> cvtpk).
// ---------------------------------------------------------------------------
__global__ __launch_bounds__(256, 3) void k_gemm1(
    const short* __restrict__ hs_bf, const float* __restrict__ wg,
    const float* __restrict__ wu, const int* __restrict__ meta,
    const int* __restrict__ slot_tok, short* __restrict__ act) {
  int nch = meta[9];
  if (blockIdx.y >= nch) return;
  int ck = meta[16 + blockIdx.y];
  int e = ck & 255;
  int row0 = ck >> 8;
  int rows = min(BM, meta[1 + e] - row0);
  int i0 = blockIdx.x * BN1;

  __shared__ short sA[4][BM * BK];       // 32KB ring-4, swizzled 64B rows
  __shared__ short sB[2][2][BN1 * BK];   // 16KB dbuf x {gate,up}, swizzled

  int tid = threadIdx.x;
  int lane = tid & 63;
  int w = tid >> 6;                 // 0..3
  int wm = w >> 1, wn = w & 1;      // 2m x 2n
  int lr = lane & 15;
  int g = lane >> 4;                // 16B granule / k-slot

  const float* wgE = wg + (size_t)e * H_ * I_;
  const float* wuE = wu + (size_t)e * H_ * I_;

  // A staging: wave w stages rows [32w,32w+32) via 2 glls; inverse swizzle
  // on the per-lane GLOBAL source granule (LDS dest linear).
  int r_a0 = 32 * w + (lane >> 2);
  int r_a1 = r_a0 + 16;
  int tok0 = slot_tok[row0 + min(r_a0, rows - 1)];
  int tok1 = slot_tok[row0 + min(r_a1, rows - 1)];
  const short* srcA0 = hs_bf + (size_t)tok0 * H_ + ((((lane & 3) ^ rswz(r_a0)) & 3) << 3);
  const short* srcA1 = hs_bf + (size_t)tok1 * H_ + ((((lane & 3) ^ rswz(r_a1)) & 3) << 3);

  // B staging: thread owns one mat, 4 k-rows x 4 n-cols.
  int mat = tid >> 7;               // 0 gate, 1 up
  int kq = (tid >> 4) & 7;          // k-quad: rows 4kq..4kq+3
  int nq = tid & 15;                // n-quad: cols 4nq..4nq+3
  const float* srcB = (mat ? wuE : wgE) + (size_t)(4 * kq) * I_ + i0 + 4 * nq;

  f32x4 accg[4][2], accu[4][2];
#pragma unroll
  for (int mf = 0; mf < 4; ++mf)
#pragma unroll
    for (int nf = 0; nf < 2; ++nf) {
      accg[mf][nf] = (f32x4){0.f, 0.f, 0.f, 0.f};
      accu[mf][nf] = (f32x4){0.f, 0.f, 0.f, 0.f};
    }

  f32x4 bs0[4], bs1[4];   // two B-staging reg sets (static-indexed)

  const int NT = H_ / BK;   // 32

  // prologue: tiles 0,1 in flight; convert tile 0 -> sB[0]; drain
  gll16(srcA0, &sA[0][(32 * w) * 32]);
  gll16(srcA1, &sA[0][(32 * w + 16) * 32]);
#pragma unroll
  for (int j = 0; j < 4; ++j) bs0[j] = *(const f32x4*)(srcB + (size_t)j * I_);
  gll16(srcA0 + BK, &sA[1][(32 * w) * 32]);
  gll16(srcA1 + BK, &sA[1][(32 * w + 16) * 32]);
#pragma unroll
  for (int j = 0; j < 4; ++j) bs1[j] = *(const f32x4*)(srcB + (size_t)(BK + j) * I_);
  {
    char* dst = (char*)&sB[0][mat][0];
#pragma unroll
    for (int c = 0; c < 4; ++c) {
      int n = 4 * nq + c;
      uint2v wv;
      wv.x = cvtpk(bs0[0][c], bs0[1][c]);
      wv.y = cvtpk(bs0[2][c], bs0[3][c]);
      *(uint2v*)(dst + tile_addr(n, kq >> 1) + ((kq & 1) << 3)) = wv;
    }
  }
  drain_barrier();

#define G1_ITER(U, bsL, bsC) do {                                              \
    int t_ = base + (U);                                                       \
    const char* curA = (const char*)&sA[t_ & 3][0];                            \
    if (t_ + 2 < NT) {                                                         \
      short* nxtA = &sA[(t_ + 2) & 3][0];                                      \
      gll16(srcA0 + (size_t)(t_ + 2) * BK, nxtA + (32 * w) * 32);              \
      gll16(srcA1 + (size_t)(t_ + 2) * BK, nxtA + (32 * w + 16) * 32);         \
      const float* sb = srcB + (size_t)(t_ + 2) * BK * I_;                     \
      bsL[0] = *(const f32x4*)(sb);                                            \
      bsL[1] = *(const f32x4*)(sb + I_);                                       \
      bsL[2] = *(const f32x4*)(sb + 2 * I_);                                   \
      bsL[3] = *(const f32x4*)(sb + 3 * I_);                                   \
    }                                                                          \
    bf16x8 a0 = *(const bf16x8*)(curA + tile_addr(wm * 64 + lr, g));           \
    bf16x8 a1 = *(const bf16x8*)(curA + tile_addr(wm * 64 + 16 + lr, g));      \
    bf16x8 a2 = *(const bf16x8*)(curA + tile_addr(wm * 64 + 32 + lr, g));      \
    bf16x8 a3 = *(const bf16x8*)(curA + tile_addr(wm * 64 + 48 + lr, g));      \
    const char* pg = (const char*)&sB[(U)][0][0];                              \
    const char* pu = (const char*)&sB[(U)][1][0];                              \
    unsigned ob0 = tile_addr(wn * 32 + lr, g);                                 \
    unsigned ob1 = tile_addr(wn * 32 + 16 + lr, g);                            \
    bf16x8 g0 = *(const bf16x8*)(pg + ob0);                                    \
    bf16x8 g1 = *(const bf16x8*)(pg + ob1);                                    \
    bf16x8 u0 = *(const bf16x8*)(pu + ob0);                                    \
    bf16x8 u1 = *(const bf16x8*)(pu + ob1);                                    \
    accg[0][0] = MFMA_BF16(a0, g0, accg[0][0], 0, 0, 0);                       \
    accg[0][1] = MFMA_BF16(a0, g1, accg[0][1], 0, 0, 0);                       \
    accg[1][0] = MFMA_BF16(a1, g0, accg[1][0], 0, 0, 0);                       \
    accg[1][1] = MFMA_BF16(a1, g1, accg[1][1], 0, 0, 0);                       \
    accg[2][0] = MFMA_BF16(a2, g0, accg[2][0], 0, 0, 0);                       \
    accg[2][1] = MFMA_BF16(a2, g1, accg[2][1], 0, 0, 0);                       \
    accg[3][0] = MFMA_BF16(a3, g0, accg[3][0], 0, 0, 0);                       \
    accg[3][1] = MFMA_BF16(a3, g1, accg[3][1], 0, 0, 0);                       \
    accu[0][0] = MFMA_BF16(a0, u0, accu[0][0], 0, 0, 0);                       \
    accu[0][1] = MFMA_BF16(a0, u1, accu[0][1], 0, 0, 0);                       \
    accu[1][0] = MFMA_BF16(a1, u0, accu[1][0], 0, 0, 0);                       \
    accu[1][1] = MFMA_BF16(a1, u1, accu[1][1], 0, 0, 0);                       \
    accu[2][0] = MFMA_BF16(a2, u0, accu[2][0], 0, 0, 0);                       \
    accu[2][1] = MFMA_BF16(a2, u1, accu[2][1], 0, 0, 0);                       \
    accu[3][0] = MFMA_BF16(a3, u0, accu[3][0], 0, 0, 0);                       \
    accu[3][1] = MFMA_BF16(a3, u1, accu[3][1], 0, 0, 0);                       \
    if (t_ + 1 < NT) {                                                         \
      char* dst = (char*)&sB[(U) ^ 1][mat][0];                                 \
      _Pragma("unroll")                                                        \
      for (int c = 0; c < 4; ++c) {                                            \
        int n = 4 * nq + c;                                                    \
        uint2v wv;                                                             \
        wv.x = cvtpk(bsC[0][c], bsC[1][c]);                                    \
        wv.y = cvtpk(bsC[2][c], bsC[3][c]);                                    \
        *(uint2v*)(dst + tile_addr(n, kq >> 1) + ((kq & 1) << 3)) = wv;        \
      }                                                                        \
    }                                                                          \
    pipe_barrier6();                                                           \
  } while (0)

  for (int base = 0; base < NT; base += 2) {
    G1_ITER(0, bs0, bs1);
    G1_ITER(1, bs1, bs0);
  }
#undef G1_ITER

  // epilogue: silu(g)*u -> bf16 act
#pragma unroll
  for (int mf = 0; mf < 4; ++mf) {
#pragma unroll
    for (int r = 0; r < 4; ++r) {
      int m = wm * 64 + mf * 16 + g * 4 + r;
      if (m < rows) {
#pragma unroll
        for (int nf = 0; nf < 2; ++nf) {
          float gv = accg[mf][nf][r];
          float uv = accu[mf][nf][r];
          float sg = 1.0f / (1.0f + __expf(-gv));
          act[(size_t)(row0 + m) * I_ + i0 + wn * 32 + nf * 16 + lr] = f2bf(gv * sg * uv);
        }
      }
    }
  }
}

// ---------------------------------------------------------------------------
// Kernel 2: grouped GEMM  out[tok,h] += w * (act[slot,:] @ Wd[e])  [round-6]
// 512 thr (8 waves, 4m x 2n, wave-tile 32x32), split-K x2, depth-3 pipeline:
// sA ring-4 linear via gll, sB ring-2 bswz, B reg ring-4, vmcnt(6).
// ---------------------------------------------------------------------------
__global__ __launch_bounds__(512, 4) void k_gemm2(
    const short* __restrict__ act, const float* __restrict__ wd,
    const int* __restrict__ meta, const int* __restrict__ slot_tok,
    const float* __restrict__ slot_w, float* __restrict__ out) {
  int nch = meta[9];
  if (blockIdx.y >= nch) return;
  int ck = meta[16 + blockIdx.y];
  int e = ck & 255;
  int row0 = ck >> 8;
  int rows = min(BM, meta[1 + e] - row0);
  int h0 = blockIdx.x * BN2;
  int kbase = blockIdx.z * (I_ / SPLITK2);

  __shared__ short sA[4][BM * BK];   // ring-4, linear [row][k]
  __shared__ short sB[2][BN2 * BK];  // ring-2, swizzled [n][k]

  int tid = threadIdx.x;
  int lane = tid & 63;
  int w = tid >> 6;
  int wm = w >> 1, wn = w & 1;
  int lr = lane & 15;
  int lk = (lane >> 4) * 8;

  const float* wdE = wd + (size_t)e * I_ * H_;

  int ra = min(16 * w + (lane >> 2), rows - 1);
  const short* srcA = act + (size_t)(row0 + ra) * I_ + kbase + (lane & 3) * 8;
  int up = tid >> 5;                   // k-pair 0..15
  int n2 = (tid & 31) * 2;
  const float* srcB = wdE + (size_t)(kbase + 2 * up) * H_ + h0 + n2;

  f32x4 acc[2][2];
#pragma unroll
  for (int mr = 0; mr < 2; ++mr)
#pragma unroll
    for (int nr = 0; nr < 2; ++nr)
      acc[mr][nr] = (f32x4){0.f, 0.f, 0.f, 0.f};

  float2 bs[4][2];   // B reg ring-4

  // prologue: tiles 0,1,2
#pragma unroll
  for (int p = 0; p < 3; ++p) {
    gll16(srcA + p * BK, &sA[p][w * 512]);
    bs[p][0] = *(const float2*)(srcB + (size_t)(p * BK) * H_);
    bs[p][1] = *(const float2*)(srcB + (size_t)(p * BK + 1) * H_);
  }
  *(unsigned*)((char*)&sB[0][0] + bswz(n2, 4 * up))     = cvtpk(bs[0][0].x, bs[0][1].x);
  *(unsigned*)((char*)&sB[0][0] + bswz(n2 + 1, 4 * up)) = cvtpk(bs[0][0].y, bs[0][1].y);
  drain_barrier();

  const int NT = (I_ / SPLITK2) / BK;   // 32

#define G2_ITER(U, base_) do {                                                 \
    int t_ = (base_) + (U);                                                    \
    if (t_ + 3 < NT) {                                                         \
      int k3 = (t_ + 3) * BK;                                                  \
      gll16(srcA + k3, &sA[((U) + 3) & 3][w * 512]);                           \
      bs[((U) + 3) & 3][0] = *(const float2*)(srcB + (size_t)k3 * H_);         \
      bs[((U) + 3) & 3][1] = *(const float2*)(srcB + (size_t)(k3 + 1) * H_);   \
    }                                                                          \
    bf16x8 a0 = *(const bf16x8*)&sA[(U)][(wm * 32 + lr) * BK + lk];            \
    bf16x8 a1 = *(const bf16x8*)&sA[(U)][(wm * 32 + 16 + lr) * BK + lk];       \
    bf16x8 b0 = *(const bf16x8*)((const char*)&sB[(U) & 1][0]                  \
                                 + bswz(wn * 32 + lr, lk * 2));                \
    bf16x8 b1 = *(const bf16x8*)((const char*)&sB[(U) & 1][0]                  \
                                 + bswz(wn * 32 + 16 + lr, lk * 2));           \
    acc[0][0] = MFMA_BF16(a0, b0, acc[0][0], 0, 0, 0);                         \
    acc[0][1] = MFMA_BF16(a0, b1, acc[0][1], 0, 0, 0);                         \
    acc[1][0] = MFMA_BF16(a1, b0, acc[1][0], 0, 0, 0);                         \
    acc[1][1] = MFMA_BF16(a1, b1, acc[1][1], 0, 0, 0);                         \
    if (t_ + 1 < NT) {                                                         \
      int s_ = ((U) + 1) & 3;                                                  \
      *(unsigned*)((char*)&sB[((U) + 1) & 1][0] + bswz(n2, 4 * up))            \
          = cvtpk(bs[s_][0].x, bs[s_][1].x);                                   \
      *(unsigned*)((char*)&sB[((U) + 1) & 1][0] + bswz(n2 + 1, 4 * up))        \
          = cvtpk(bs[s_][0].y, bs[s_][1].y);                                   \
    }                                                                          \
    pipe_barrier6();                                                           \
  } while (0)

  for (int base = 0; base < NT; base += 4) {
    G2_ITER(0, base);
    G2_ITER(1, base);
    G2_ITER(2, base);
    G2_ITER(3, base);
  }
#undef G2_ITER

  // epilogue: scale by combine weight, scatter-add
#pragma unroll
  for (int mr = 0; mr < 2; ++mr) {
#pragma unroll
    for (int r = 0; r < 4; ++r) {
      int m = wm * 32 + mr * 16 + (lane >> 4) * 4 + r;
      if (m < rows) {
        int gs = row0 + m;
        float wc = slot_w[gs];
        int tok = slot_tok[gs];
#pragma unroll
        for (int nr = 0; nr < 2; ++nr)
          atomicAdd(&out[(size_t)tok * H_ + h0 + wn * 32 + nr * 16 + lr],
                    acc[mr][nr][r] * wc);
      }
    }
  }
}

// ---------------------------------------------------------------------------
extern "C" void kernel_launch(void* const* d_in, const int* in_sizes, int n_in,
                              void* d_out, int out_size, void* d_ws, size_t ws_size,
                              hipStream_t stream) {
  const float* hs   = (const float*)d_in[0];
  const float* aff  = (const float*)d_in[1];
  const int*   eidx = (const int*)d_in[2];
  const float* wg   = (const float*)d_in[3];
  const float* wu   = (const float*)d_in[4];
  const float* wd   = (const float*)d_in[5];
  float* out = (float*)d_out;

  char* ws = (char*)d_ws;
  int*   meta     = (int*)ws;                            // 256B reserved
  int*   slot_tok = (int*)(ws + 256);                    // 2048 ints
  float* slot_w   = (float*)(ws + 256 + NSLOT * 4);      // 2048 floats
  short* hs_bf    = (short*)(ws + 256 + NSLOT * 8);      // 2MB bf16 hs
  short* act      = (short*)(ws + 256 + NSLOT * 8 + (size_t)T_ * H_ * 2);  // 8MB

  hipMemsetAsync(d_out, 0, (size_t)out_size * sizeof(float), stream);
  k_prep_build<<<(T_ * H_) / (256 * 8), 256, 0, stream>>>(
      hs, hs_bf, aff, eidx, meta, slot_tok, slot_w);
  k_gemm1<<<dim3(I_ / BN1, NCHUNK_CAP), 256, 0, stream>>>(
      hs_bf, wg, wu, meta, slot_tok, act);
  k_gemm2<<<dim3(H_ / BN2, NCHUNK_CAP, SPLITK2), 512, 0, stream>>>(
      act, wd, meta, slot_tok, slot_w, out);
}

// Round 16
// 96.216 us; speedup vs baseline: 1.2913x; 1.0550x over previous
//
#include <hip/hip_runtime.h>
#include <hip/hip_bf16.h>
#include <math.h>

// Problem constants (fixed shape)
#define T_ 1024
#define H_ 1024
#define I_ 2048
#define E_ 8
#define NSLOT 2048

// GEMM tiling
#define BM 128
#define BK 32
#define BN1 64                      // gemm1 n-tile
#define BN2 64                      // gemm2 n-tile
#define NCHUNK_CAP 24               // sum ceil(cnt_e/128) <= 23
#define SPLITK2 2                   // gemm2 split-K (I=2048 -> 2x1024)

typedef __attribute__((ext_vector_type(8))) short bf16x8;
typedef __attribute__((ext_vector_type(4))) float f32x4;
typedef __attribute__((ext_vector_type(4))) unsigned uint4v;
typedef __attribute__((ext_vector_type(2))) unsigned uint2v;

#define MFMA_BF16 __builtin_amdgcn_mfma_f32_16x16x32_bf16

__device__ __forceinline__ short f2bf(float f) {
  union { float f; unsigned u; } v; v.f = f;
  unsigned r = v.u + 0x7FFFu + ((v.u >> 16) & 1u);
  return (short)(r >> 16);
}
__device__ __forceinline__ unsigned cvtpk(float lo, float hi) {
  unsigned r;
  asm("v_cvt_pk_bf16_f32 %0, %1, %2" : "=v"(r) : "v"(lo), "v"(hi));
  return r;
}
// async 16B global->LDS (lane i writes lds_base + i*16)
__device__ __forceinline__ void gll16(const void* g, void* l) {
  __builtin_amdgcn_global_load_lds(
      (const __attribute__((address_space(1))) void*)g,
      (__attribute__((address_space(3))) void*)l, 16, 0, 0);
}

// Counted-vmcnt pipelined barrier: allow 6 vmem (one iteration's issue for
// gemm1 depth-2 / two iterations' for gemm2 depth-3) to stay in flight.
__device__ __forceinline__ void pipe_barrier6() {
  __builtin_amdgcn_sched_barrier(0);
  asm volatile("s_waitcnt vmcnt(6) lgkmcnt(0)" ::: "memory");
  __builtin_amdgcn_s_barrier();
  __builtin_amdgcn_sched_barrier(0);
}
__device__ __forceinline__ void drain_barrier() {
  __builtin_amdgcn_sched_barrier(0);
  asm volatile("s_waitcnt vmcnt(0) lgkmcnt(0)" ::: "memory");
  __builtin_amdgcn_s_barrier();
  __builtin_amdgcn_sched_barrier(0);
}

// B-tile swizzle ([n][k] bf16, rows of 64B) — round-4/6 gemm2 layout.
__device__ __forceinline__ unsigned bswz(int n, int kbyte) {
  return (unsigned)(n * 64 + (kbyte ^ (((n >> 2) & 3) << 4)));
}
// Unified tile swizzle ([rows][32] bf16, four 16B granules) — round-7 gemm1.
__device__ __forceinline__ int rswz(int row) { return (row >> 1) & 3; }
__device__ __forceinline__ unsigned tile_addr(int row, int g) {
  return (unsigned)(row * 64 + (((g ^ rswz(row)) & 3) << 4));
}

// ---------------------------------------------------------------------------
// Kernel 0: fused hs f32->bf16 convert + out zeroing (all blocks)
//           + routing build (block 0)
// meta[0..8]=offs, meta[9]=nchunks, meta[16+c] = e | (row0<<8)
// ---------------------------------------------------------------------------
__global__ __launch_bounds__(256) void k_prep_build(
    const float* __restrict__ hs, short* __restrict__ hs_bf,
    const float* __restrict__ aff, const int* __restrict__ eidx,
    int* __restrict__ meta, int* __restrict__ slot_tok, float* __restrict__ slot_w,
    float* __restrict__ out) {
  // ---- prep slice (all 512 blocks): convert 8 floats + zero 8 out floats ----
  int i = (blockIdx.x * 256 + threadIdx.x) * 8;
  float4 v0 = *(const float4*)&hs[i];
  float4 v1 = *(const float4*)&hs[i + 4];
  uint4v p;
  p.x = cvtpk(v0.x, v0.y); p.y = cvtpk(v0.z, v0.w);
  p.z = cvtpk(v1.x, v1.y); p.w = cvtpk(v1.z, v1.w);
  *(uint4v*)&hs_bf[i] = p;
  float4 z = {0.f, 0.f, 0.f, 0.f};
  *(float4*)&out[i] = z;
  *(float4*)&out[i + 4] = z;

  // ---- build (block 0 only): 256 threads x 4 tokens each ----
  if (blockIdx.x != 0) return;
  __shared__ int cnt[E_];
  __shared__ int soff[E_ + 1];
  int t = threadIdx.x;
  if (t < E_) cnt[t] = 0;
  __syncthreads();
  int e0a[4], e1a[4], r0a[4], r1a[4];
  float w0a[4], w1a[4];
#pragma unroll
  for (int j = 0; j < 4; ++j) {
    int tok = t + 256 * j;
    int e0 = eidx[tok * 2 + 0];
    int e1 = eidx[tok * 2 + 1];
    float a0 = aff[tok * E_ + e0];
    float a1 = aff[tok * E_ + e1];
    float inv = 1.0f / (a0 + a1);
    r0a[j] = atomicAdd(&cnt[e0], 1);
    r1a[j] = atomicAdd(&cnt[e1], 1);
    e0a[j] = e0; e1a[j] = e1;
    w0a[j] = a0 * inv; w1a[j] = a1 * inv;
  }
  __syncthreads();
  if (t == 0) {
    int s = 0;
    for (int e = 0; e < E_; ++e) { soff[e] = s; s += cnt[e]; }
    soff[E_] = s;
    int nc = 0;
    for (int e = 0; e < E_; ++e)
      for (int c = soff[e]; c < soff[e] + cnt[e]; c += BM)
        meta[16 + nc++] = e | (c << 8);
    meta[9] = nc;
  }
  __syncthreads();
  if (t <= E_) meta[t] = soff[t];
#pragma unroll
  for (int j = 0; j < 4; ++j) {
    int tok = t + 256 * j;
    int s0 = soff[e0a[j]] + r0a[j];
    int s1 = soff[e1a[j]] + r1a[j];
    slot_tok[s0] = tok; slot_w[s0] = w0a[j];
    slot_tok[s1] = tok; slot_w[s1] = w1a[j];
  }
}

// ---------------------------------------------------------------------------
// Kernel 1: grouped GEMM  act[slot,i] = silu(X@Wg) * (X@Wu)   [round-7 form]
// 256 thr (4 waves, 2m x 2n), wave-tile 64x32 per mat (Mf=4, Nf=2):
// 8 LDS reads feed 16 MFMA. Depth-2 counted-vmcnt pipeline:
// sA ring-4 (source-swizzled gll), sB dbuf (reg-staged f32 -> cvtpk).
// ---------------------------------------------------------------------------
__global__ __launch_bounds__(256, 3) void k_gemm1(
    const short* __restrict__ hs_bf, const float* __restrict__ wg,
    const float* __restrict__ wu, const int* __restrict__ meta,
    const int* __restrict__ slot_tok, short* __restrict__ act) {
  int nch = meta[9];
  if (blockIdx.y >= nch) return;
  int ck = meta[16 + blockIdx.y];
  int e = ck & 255;
  int row0 = ck >> 8;
  int rows = min(BM, meta[1 + e] - row0);
  int i0 = blockIdx.x * BN1;

  __shared__ short sA[4][BM * BK];       // 32KB ring-4, swizzled 64B rows
  __shared__ short sB[2][2][BN1 * BK];   // 16KB dbuf x {gate,up}, swizzled

  int tid = threadIdx.x;
  int lane = tid & 63;
  int w = tid >> 6;                 // 0..3
  int wm = w >> 1, wn = w & 1;      // 2m x 2n
  int lr = lane & 15;
  int g = lane >> 4;                // 16B granule / k-slot

  const float* wgE = wg + (size_t)e * H_ * I_;
  const float* wuE = wu + (size_t)e * H_ * I_;

  // A staging: wave w stages rows [32w,32w+32) via 2 glls; inverse swizzle
  // on the per-lane GLOBAL source granule (LDS dest linear).
  int r_a0 = 32 * w + (lane >> 2);
  int r_a1 = r_a0 + 16;
  int tok0 = slot_tok[row0 + min(r_a0, rows - 1)];
  int tok1 = slot_tok[row0 + min(r_a1, rows - 1)];
  const short* srcA0 = hs_bf + (size_t)tok0 * H_ + ((((lane & 3) ^ rswz(r_a0)) & 3) << 3);
  const short* srcA1 = hs_bf + (size_t)tok1 * H_ + ((((lane & 3) ^ rswz(r_a1)) & 3) << 3);

  // B staging: thread owns one mat, 4 k-rows x 4 n-cols.
  int mat = tid >> 7;               // 0 gate, 1 up
  int kq = (tid >> 4) & 7;          // k-quad: rows 4kq..4kq+3
  int nq = tid & 15;                // n-quad: cols 4nq..4nq+3
  const float* srcB = (mat ? wuE : wgE) + (size_t)(4 * kq) * I_ + i0 + 4 * nq;

  f32x4 accg[4][2], accu[4][2];
#pragma unroll
  for (int mf = 0; mf < 4; ++mf)
#pragma unroll
    for (int nf = 0; nf < 2; ++nf) {
      accg[mf][nf] = (f32x4){0.f, 0.f, 0.f, 0.f};
      accu[mf][nf] = (f32x4){0.f, 0.f, 0.f, 0.f};
    }

  f32x4 bs0[4], bs1[4];   // two B-staging reg sets (static-indexed)

  const int NT = H_ / BK;   // 32

  // prologue: tiles 0,1 in flight; convert tile 0 -> sB[0]; drain
  gll16(srcA0, &sA[0][(32 * w) * 32]);
  gll16(srcA1, &sA[0][(32 * w + 16) * 32]);
#pragma unroll
  for (int j = 0; j < 4; ++j) bs0[j] = *(const f32x4*)(srcB + (size_t)j * I_);
  gll16(srcA0 + BK, &sA[1][(32 * w) * 32]);
  gll16(srcA1 + BK, &sA[1][(32 * w + 16) * 32]);
#pragma unroll
  for (int j = 0; j < 4; ++j) bs1[j] = *(const f32x4*)(srcB + (size_t)(BK + j) * I_);
  {
    char* dst = (char*)&sB[0][mat][0];
#pragma unroll
    for (int c = 0; c < 4; ++c) {
      int n = 4 * nq + c;
      uint2v wv;
      wv.x = cvtpk(bs0[0][c], bs0[1][c]);
      wv.y = cvtpk(bs0[2][c], bs0[3][c]);
      *(uint2v*)(dst + tile_addr(n, kq >> 1) + ((kq & 1) << 3)) = wv;
    }
  }
  drain_barrier();

#define G1_ITER(U, bsL, bsC) do {                                              \
    int t_ = base + (U);                                                       \
    const char* curA = (const char*)&sA[t_ & 3][0];                            \
    if (t_ + 2 < NT) {                                                         \
      short* nxtA = &sA[(t_ + 2) & 3][0];                                      \
      gll16(srcA0 + (size_t)(t_ + 2) * BK, nxtA + (32 * w) * 32);              \
      gll16(srcA1 + (size_t)(t_ + 2) * BK, nxtA + (32 * w + 16) * 32);         \
      const float* sb = srcB + (size_t)(t_ + 2) * BK * I_;                     \
      bsL[0] = *(const f32x4*)(sb);                                            \
      bsL[1] = *(const f32x4*)(sb + I_);                                       \
      bsL[2] = *(const f32x4*)(sb + 2 * I_);                                   \
      bsL[3] = *(const f32x4*)(sb + 3 * I_);                                   \
    }                                                                          \
    bf16x8 a0 = *(const bf16x8*)(curA + tile_addr(wm * 64 + lr, g));           \
    bf16x8 a1 = *(const bf16x8*)(curA + tile_addr(wm * 64 + 16 + lr, g));      \
    bf16x8 a2 = *(const bf16x8*)(curA + tile_addr(wm * 64 + 32 + lr, g));      \
    bf16x8 a3 = *(const bf16x8*)(curA + tile_addr(wm * 64 + 48 + lr, g));      \
    const char* pg = (const char*)&sB[(U)][0][0];                              \
    const char* pu = (const char*)&sB[(U)][1][0];                              \
    unsigned ob0 = tile_addr(wn * 32 + lr, g);                                 \
    unsigned ob1 = tile_addr(wn * 32 + 16 + lr, g);                            \
    bf16x8 g0 = *(const bf16x8*)(pg + ob0);                                    \
    bf16x8 g1 = *(const bf16x8*)(pg + ob1);                                    \
    bf16x8 u0 = *(const bf16x8*)(pu + ob0);                                    \
    bf16x8 u1 = *(const bf16x8*)(pu + ob1);                                    \
    accg[0][0] = MFMA_BF16(a0, g0, accg[0][0], 0, 0, 0);                       \
    accg[0][1] = MFMA_BF16(a0, g1, accg[0][1], 0, 0, 0);                       \
    accg[1][0] = MFMA_BF16(a1, g0, accg[1][0], 0, 0, 0);                       \
    accg[1][1] = MFMA_BF16(a1, g1, accg[1][1], 0, 0, 0);                       \
    accg[2][0] = MFMA_BF16(a2, g0, accg[2][0], 0, 0, 0);                       \
    accg[2][1] = MFMA_BF16(a2, g1, accg[2][1], 0, 0, 0);                       \
    accg[3][0] = MFMA_BF16(a3, g0, accg[3][0], 0, 0, 0);                       \
    accg[3][1] = MFMA_BF16(a3, g1, accg[3][1], 0, 0, 0);                       \
    accu[0][0] = MFMA_BF16(a0, u0, accu[0][0], 0, 0, 0);                       \
    accu[0][1] = MFMA_BF16(a0, u1, accu[0][1], 0, 0, 0);                       \
    accu[1][0] = MFMA_BF16(a1, u0, accu[1][0], 0, 0, 0);                       \
    accu[1][1] = MFMA_BF16(a1, u1, accu[1][1], 0, 0, 0);                       \
    accu[2][0] = MFMA_BF16(a2, u0, accu[2][0], 0, 0, 0);                       \
    accu[2][1] = MFMA_BF16(a2, u1, accu[2][1], 0, 0, 0);                       \
    accu[3][0] = MFMA_BF16(a3, u0, accu[3][0], 0, 0, 0);                       \
    accu[3][1] = MFMA_BF16(a3, u1, accu[3][1], 0, 0, 0);                       \
    if (t_ + 1 < NT) {                                                         \
      char* dst = (char*)&sB[(U) ^ 1][mat][0];                                 \
      _Pragma("unroll")                                                        \
      for (int c = 0; c < 4; ++c) {                                            \
        int n = 4 * nq + c;                                                    \
        uint2v wv;                                                             \
        wv.x = cvtpk(bsC[0][c], bsC[1][c]);                                    \
        wv.y = cvtpk(bsC[2][c], bsC[3][c]);                                    \
        *(uint2v*)(dst + tile_addr(n, kq >> 1) + ((kq & 1) << 3)) = wv;        \
      }                                                                        \
    }                                                                          \
    pipe_barrier6();                                                           \
  } while (0)

  for (int base = 0; base < NT; base += 2) {
    G1_ITER(0, bs0, bs1);
    G1_ITER(1, bs1, bs0);
  }
#undef G1_ITER

  // epilogue: silu(g)*u -> bf16 act
#pragma unroll
  for (int mf = 0; mf < 4; ++mf) {
#pragma unroll
    for (int r = 0; r < 4; ++r) {
      int m = wm * 64 + mf * 16 + g * 4 + r;
      if (m < rows) {
#pragma unroll
        for (int nf = 0; nf < 2; ++nf) {
          float gv = accg[mf][nf][r];
          float uv = accu[mf][nf][r];
          float sg = 1.0f / (1.0f + __expf(-gv));
          act[(size_t)(row0 + m) * I_ + i0 + wn * 32 + nf * 16 + lr] = f2bf(gv * sg * uv);
        }
      }
    }
  }
}

// ---------------------------------------------------------------------------
// Kernel 2: grouped GEMM  out[tok,h] += w * (act[slot,:] @ Wd[e])  [round-6]
// 512 thr (8 waves, 4m x 2n, wave-tile 32x32), split-K x2, depth-3 pipeline:
// sA ring-4 linear via gll, sB ring-2 bswz, B reg ring-4, vmcnt(6).
// ---------------------------------------------------------------------------
__global__ __launch_bounds__(512, 4) void k_gemm2(
    const short* __restrict__ act, const float* __restrict__ wd,
    const int* __restrict__ meta, const int* __restrict__ slot_tok,
    const float* __restrict__ slot_w, float* __restrict__ out) {
  int nch = meta[9];
  if (blockIdx.y >= nch) return;
  int ck = meta[16 + blockIdx.y];
  int e = ck & 255;
  int row0 = ck >> 8;
  int rows = min(BM, meta[1 + e] - row0);
  int h0 = blockIdx.x * BN2;
  int kbase = blockIdx.z * (I_ / SPLITK2);

  __shared__ short sA[4][BM * BK];   // ring-4, linear [row][k]
  __shared__ short sB[2][BN2 * BK];  // ring-2, swizzled [n][k]

  int tid = threadIdx.x;
  int lane = tid & 63;
  int w = tid >> 6;
  int wm = w >> 1, wn = w & 1;
  int lr = lane & 15;
  int lk = (lane >> 4) * 8;

  const float* wdE = wd + (size_t)e * I_ * H_;

  int ra = min(16 * w + (lane >> 2), rows - 1);
  const short* srcA = act + (size_t)(row0 + ra) * I_ + kbase + (lane & 3) * 8;
  int up = tid >> 5;                   // k-pair 0..15
  int n2 = (tid & 31) * 2;
  const float* srcB = wdE + (size_t)(kbase + 2 * up) * H_ + h0 + n2;

  f32x4 acc[2][2];
#pragma unroll
  for (int mr = 0; mr < 2; ++mr)
#pragma unroll
    for (int nr = 0; nr < 2; ++nr)
      acc[mr][nr] = (f32x4){0.f, 0.f, 0.f, 0.f};

  float2 bs[4][2];   // B reg ring-4

  // prologue: tiles 0,1,2
#pragma unroll
  for (int p = 0; p < 3; ++p) {
    gll16(srcA + p * BK, &sA[p][w * 512]);
    bs[p][0] = *(const float2*)(srcB + (size_t)(p * BK) * H_);
    bs[p][1] = *(const float2*)(srcB + (size_t)(p * BK + 1) * H_);
  }
  *(unsigned*)((char*)&sB[0][0] + bswz(n2, 4 * up))     = cvtpk(bs[0][0].x, bs[0][1].x);
  *(unsigned*)((char*)&sB[0][0] + bswz(n2 + 1, 4 * up)) = cvtpk(bs[0][0].y, bs[0][1].y);
  drain_barrier();

  const int NT = (I_ / SPLITK2) / BK;   // 32

#define G2_ITER(U, base_) do {                                                 \
    int t_ = (base_) + (U);                                                    \
    if (t_ + 3 < NT) {                                                         \
      int k3 = (t_ + 3) * BK;                                                  \
      gll16(srcA + k3, &sA[((U) + 3) & 3][w * 512]);                           \
      bs[((U) + 3) & 3][0] = *(const float2*)(srcB + (size_t)k3 * H_);         \
      bs[((U) + 3) & 3][1] = *(const float2*)(srcB + (size_t)(k3 + 1) * H_);   \
    }                                                                          \
    bf16x8 a0 = *(const bf16x8*)&sA[(U)][(wm * 32 + lr) * BK + lk];            \
    bf16x8 a1 = *(const bf16x8*)&sA[(U)][(wm * 32 + 16 + lr) * BK + lk];       \
    bf16x8 b0 = *(const bf16x8*)((const char*)&sB[(U) & 1][0]                  \
                                 + bswz(wn * 32 + lr, lk * 2));                \
    bf16x8 b1 = *(const bf16x8*)((const char*)&sB[(U) & 1][0]                  \
                                 + bswz(wn * 32 + 16 + lr, lk * 2));           \
    acc[0][0] = MFMA_BF16(a0, b0, acc[0][0], 0, 0, 0);                         \
    acc[0][1] = MFMA_BF16(a0, b1, acc[0][1], 0, 0, 0);                         \
    acc[1][0] = MFMA_BF16(a1, b0, acc[1][0], 0, 0, 0);                         \
    acc[1][1] = MFMA_BF16(a1, b1, acc[1][1], 0, 0, 0);                         \
    if (t_ + 1 < NT) {                                                         \
      int s_ = ((U) + 1) & 3;                                                  \
      *(unsigned*)((char*)&sB[((U) + 1) & 1][0] + bswz(n2, 4 * up))            \
          = cvtpk(bs[s_][0].x, bs[s_][1].x);                                   \
      *(unsigned*)((char*)&sB[((U) + 1) & 1][0] + bswz(n2 + 1, 4 * up))        \
          = cvtpk(bs[s_][0].y, bs[s_][1].y);                                   \
    }                                                                          \
    pipe_barrier6();                                                           \
  } while (0)

  for (int base = 0; base < NT; base += 4) {
    G2_ITER(0, base);
    G2_ITER(1, base);
    G2_ITER(2, base);
    G2_ITER(3, base);
  }
#undef G2_ITER

  // epilogue: scale by combine weight, scatter-add
#pragma unroll
  for (int mr = 0; mr < 2; ++mr) {
#pragma unroll
    for (int r = 0; r < 4; ++r) {
      int m = wm * 32 + mr * 16 + (lane >> 4) * 4 + r;
      if (m < rows) {
        int gs = row0 + m;
        float wc = slot_w[gs];
        int tok = slot_tok[gs];
#pragma unroll
        for (int nr = 0; nr < 2; ++nr)
          atomicAdd(&out[(size_t)tok * H_ + h0 + wn * 32 + nr * 16 + lr],
                    acc[mr][nr][r] * wc);
      }
    }
  }
}

// ---------------------------------------------------------------------------
extern "C" void kernel_launch(void* const* d_in, const int* in_sizes, int n_in,
                              void* d_out, int out_size, void* d_ws, size_t ws_size,
                              hipStream_t stream) {
  const float* hs   = (const float*)d_in[0];
  const float* aff  = (const float*)d_in[1];
  const int*   eidx = (const int*)d_in[2];
  const float* wg   = (const float*)d_in[3];
  const float* wu   = (const float*)d_in[4];
  const float* wd   = (const float*)d_in[5];
  float* out = (float*)d_out;

  char* ws = (char*)d_ws;
  int*   meta     = (int*)ws;                            // 256B reserved
  int*   slot_tok = (int*)(ws + 256);                    // 2048 ints
  float* slot_w   = (float*)(ws + 256 + NSLOT * 4);      // 2048 floats
  short* hs_bf    = (short*)(ws + 256 + NSLOT * 8);      // 2MB bf16 hs
  short* act      = (short*)(ws + 256 + NSLOT * 8 + (size_t)T_ * H_ * 2);  // 8MB

  k_prep_build<<<(T_ * H_) / (256 * 8), 256, 0, stream>>>(
      hs, hs_bf, aff, eidx, meta, slot_tok, slot_w, out);
  k_gemm1<<<dim3(I_ / BN1, NCHUNK_CAP), 256, 0, stream>>>(
      hs_bf, wg, wu, meta, slot_tok, act);
  k_gemm2<<<dim3(H_ / BN2, NCHUNK_CAP, SPLITK2), 512, 0, stream>>>(
      act, wd, meta, slot_tok, slot_w, out);
}